// Round 5
// baseline (312.164 us; speedup 1.0000x reference)
//
#include <hip/hip_runtime.h>

#define N_VERT 35709
#define N_FACE 70789
#define NB 32
#define M3 (3*N_VERT)        // 107127

#define FSS ((size_t)N_VERT*16)      // fs slab stride (floats): [v][4b][4]
#define FNS ((size_t)(N_FACE+1)*16)  // fn slab stride (floats)

// ---- workspace layout (float offsets) ----
#define WS_FS   ((size_t)0)                  // [8 slabs][N_VERT][4][4]
#define WS_FN   (WS_FS + 8*FSS)              // [8 slabs][N_FACE+1][4][4]
#define WS_CPAD (WS_FN + 8*FNS)              // [32][256]
#define WS_ROT  (WS_CPAD + (size_t)NB*256)   // [32][9]
#define WS_TRE  (WS_ROT + (size_t)NB*9)      // [32][3]
#define WS_G    (WS_TRE + (size_t)NB*3)      // [32][27]
#define WS_MEAN (WS_G + (size_t)NB*27)       // [3]

// ---- output layout (float offsets) ----
#define FC_OFF  ((size_t)0)
#define LM_OFF  ((size_t)NB*M3)
#define FST_OFF (LM_OFF + (size_t)NB*68*2)

// ---- SH constants ----
#define A0C0 0.88622692545275801f
#define A1C1 1.77245385090551603f
#define A2C2 2.42703239430f
#define Y6C  0.70062393935f
#define Y8C  1.21351619715f

typedef float vf4 __attribute__((ext_vector_type(4)));

__device__ __forceinline__ void nt_store4(float* p, float a, float b, float c, float d) {
  vf4 v = {a, b, c, d};
  __builtin_nontemporal_store(v, (vf4*)p);
}

// ======================= Stage A1: meanshape partial sums =======================
__global__ void __launch_bounds__(256) face3d_stageA1(
    const float* __restrict__ ms, float* __restrict__ ws) {
  float s0=0.f, s1=0.f, s2=0.f;
  for (int v = blockIdx.x*256 + threadIdx.x; v < N_VERT; v += gridDim.x*256) {
    s0 += ms[3*v+0]; s1 += ms[3*v+1]; s2 += ms[3*v+2];
  }
  #pragma unroll
  for (int off = 32; off > 0; off >>= 1) {
    s0 += __shfl_down(s0, off);
    s1 += __shfl_down(s1, off);
    s2 += __shfl_down(s2, off);
  }
  if ((threadIdx.x & 63) == 0) {
    atomicAdd(&ws[WS_MEAN+0], s0);
    atomicAdd(&ws[WS_MEAN+1], s1);
    atomicAdd(&ws[WS_MEAN+2], s2);
  }
}

// ======================= Stage A2: per-batch constants =======================
__global__ void __launch_bounds__(256) face3d_stageA2(
    const float* __restrict__ coeff, float* __restrict__ ws) {
  int t = threadIdx.x;
  float m0 = ws[WS_MEAN+0]*(1.0f/N_VERT);
  float m1 = ws[WS_MEAN+1]*(1.0f/N_VERT);
  float m2 = ws[WS_MEAN+2]*(1.0f/N_VERT);
  for (int idx = t; idx < NB*256; idx += 256) {
    int b = idx >> 8, k = idx & 255;
    ws[WS_CPAD + idx] = (k < 244) ? coeff[b*277 + k] : 0.0f;
  }
  for (int idx = t; idx < NB*27; idx += 256) {
    int b = idx / 27, k = idx - b*27;
    ws[WS_G + idx] = coeff[b*277 + 247 + k] + (((k % 9) == 0) ? 0.8f : 0.0f);
  }
  if (t < NB) {
    int b = t;
    float ax = coeff[b*277+244], ay = coeff[b*277+245], az = coeff[b*277+246];
    float cx=cosf(ax), sx=sinf(ax);
    float cy=cosf(ay), sy=sinf(ay);
    float cz=cosf(az), sz=sinf(az);
    float T00=cz*cy, T01=-sz, T02=cz*sy;
    float T10=sz*cy, T11=cz,  T12=sz*sy;
    float T20=-sy,   T21=0.f, T22=cy;
    float R[3][3];
    R[0][0]=T00; R[0][1]=T01*cx+T02*sx; R[0][2]=-T01*sx+T02*cx;
    R[1][0]=T10; R[1][1]=T11*cx+T12*sx; R[1][2]=-T11*sx+T12*cx;
    R[2][0]=T20; R[2][1]=T21*cx+T22*sx; R[2][2]=-T21*sx+T22*cx;
    float rot[3][3];
    #pragma unroll
    for (int c=0;c<3;c++)
      #pragma unroll
      for (int j=0;j<3;j++)
        rot[c][j] = R[j][c];
    #pragma unroll
    for (int c=0;c<3;c++)
      #pragma unroll
      for (int j=0;j<3;j++)
        ws[WS_ROT + b*9 + c*3 + j] = rot[c][j];
    #pragma unroll
    for (int j=0;j<3;j++)
      ws[WS_TRE + b*3 + j] = coeff[b*277+274+j]
        - (m0*rot[0][j] + m1*rot[1][j] + m2*rot[2][j]);
  }
}

// ======================= Stage B: GEMMs (8 rows x 8 batches / thread) =======================
// W layout in LDS: [32 b][65 float4] (pad 64->65 breaks bank aliasing).
// Thread: bg = t&3, batches b = bg + 4j (j=0..7); rows = blk*512 + (t>>2)*8 + i.
template<int NK4, int KROW, int COFF>
__device__ __forceinline__ void phase88(const float* __restrict__ A0,
                                        int row0,
                                        const float4* __restrict__ W,
                                        int bg,
                                        float acc[8][8]) {
  const float4* p[8];
  #pragma unroll
  for (int i = 0; i < 8; ++i) {
    int r = row0 + i; if (r >= M3) r = M3-1;
    p[i] = (const float4*)(A0 + (size_t)r*KROW);
  }
  float4 cur[8];
  #pragma unroll
  for (int i = 0; i < 8; ++i) cur[i] = p[i][0];
  #pragma unroll 1
  for (int s = 0; s < NK4; ++s) {
    float4 a[8];
    #pragma unroll
    for (int i = 0; i < 8; ++i) a[i] = cur[i];
    if (s + 1 < NK4) {
      #pragma unroll
      for (int i = 0; i < 8; ++i) cur[i] = p[i][s+1];
    }
    #pragma unroll
    for (int j = 0; j < 8; ++j) {
      float4 w = W[(size_t)(bg + 4*j)*65 + COFF + s];
      #pragma unroll
      for (int i = 0; i < 8; ++i) {
        acc[i][j] = fmaf(a[i].x, w.x, fmaf(a[i].y, w.y,
                    fmaf(a[i].z, w.z, fmaf(a[i].w, w.w, acc[i][j]))));
      }
    }
  }
}

__global__ void __launch_bounds__(256,1) face3d_stageB(
    const float* __restrict__ idB, const float* __restrict__ exB,
    const float* __restrict__ texB, const float* __restrict__ meanshape,
    const float* __restrict__ meantex, const float* __restrict__ cpad,
    float* __restrict__ fsS, float* __restrict__ texOut) {
  __shared__ float4 W[32*65];
  int t = threadIdx.x;
  {
    const float4* __restrict__ src = (const float4*)cpad;
    #pragma unroll
    for (int n = 0; n < 8; ++n) {
      int idx = t + 256*n;           // 0..2047
      int b = idx >> 6, k = idx & 63;
      W[b*65 + k] = src[idx];
    }
  }
  __syncthreads();
  int bg = t & 3;
  int row0 = blockIdx.x*512 + (t >> 2)*8;
  if (row0 >= M3) return;

  float acc[8][8];
  #pragma unroll
  for (int i=0;i<8;i++)
    #pragma unroll
    for (int j=0;j<8;j++) acc[i][j]=0.f;

  phase88<20, 80, 0 >(idB, row0, W, bg, acc);
  phase88<16, 64, 20>(exB, row0, W, bg, acc);

  #pragma unroll
  for (int i = 0; i < 8; ++i) {
    int r = row0 + i;
    if (r < M3) {
      float msv = meanshape[r];
      int v = r/3, c = r - 3*v;
      float* dst = fsS + (size_t)v*16 + bg*4 + c;   // + j*FSS per batch-slab
      #pragma unroll
      for (int j = 0; j < 8; ++j)
        dst[j*FSS] = acc[i][j] + msv;               // slab j == (bg+4j)>>2
    }
  }

  #pragma unroll
  for (int i=0;i<8;i++)
    #pragma unroll
    for (int j=0;j<8;j++) acc[i][j]=0.f;

  phase88<25, 100, 36>(texB, row0, W, bg, acc);

  #pragma unroll
  for (int i = 0; i < 8; ++i) {
    int r = row0 + i;
    if (r < M3) {
      float mtv = meantex[r];
      #pragma unroll
      for (int j = 0; j < 8; ++j) {
        int b = bg + 4*j;
        __builtin_nontemporal_store(acc[i][j] + mtv, &texOut[(size_t)b*M3 + r]);
      }
    }
  }
}

// ======================= Stage C: face normals =======================
// block: slab bg = blockIdx&7 (XCD round-robin), 64 faces x 4 batches
__global__ void __launch_bounds__(256) face3d_stageC(
    const int* __restrict__ face_buf, const float* __restrict__ fsS,
    float* __restrict__ fnS) {
  int t = threadIdx.x;
  int bg = blockIdx.x & 7;
  int f = (blockIdx.x >> 3)*64 + (t >> 2);
  int bsub = t & 3;
  if (f > N_FACE) return;
  float* o = fnS + bg*FNS + (size_t)f*16 + bsub*4;
  if (f == N_FACE) {
    nt_store4(o, 0.f, 0.f, 0.f, 0.f);
    return;
  }
  int i0 = face_buf[f*3+0];
  int i1 = face_buf[f*3+1];
  int i2 = face_buf[f*3+2];
  const float* fs = fsS + bg*FSS + bsub*4;
  float4 p1 = *(const float4*)(fs + (size_t)i0*16);
  float4 p2 = *(const float4*)(fs + (size_t)i1*16);
  float4 p3 = *(const float4*)(fs + (size_t)i2*16);
  float e1x = p1.x-p2.x, e1y = p1.y-p2.y, e1z = p1.z-p2.z;
  float e2x = p2.x-p3.x, e2y = p2.y-p3.y, e2z = p2.z-p3.z;
  float nx = e1y*e2z - e1z*e2y;
  float ny = e1z*e2x - e1x*e2z;
  float nz = e1x*e2y - e1y*e2x;
  float inv = 1.0f / fmaxf(sqrtf(nx*nx + ny*ny + nz*nz), 1e-12f);
  nt_store4(o, nx*inv, ny*inv, nz*inv, 0.f);
}

// ======================= Stage D =======================
#define DVB 558   // ceil(N_VERT/64)
__global__ void __launch_bounds__(256) face3d_stageD(
    const int* __restrict__ point_buf, const int* __restrict__ keypoints,
    const float* __restrict__ fsS, const float* __restrict__ fnS,
    const float* __restrict__ rotAll, const float* __restrict__ treAll,
    const float* __restrict__ gAll, float* __restrict__ out) {
  const int mainBlocks = 8*DVB;
  int bid = blockIdx.x;
  int t = threadIdx.x;
  if (bid < mainBlocks) {
    __shared__ float fstL[4*193];
    __shared__ float LL[4*193];
    int bg = bid & 7;
    int v0 = (bid >> 3)*64;
    int bsub = t & 3, vi = t >> 2;
    int v = v0 + vi;
    int b = bg*4 + bsub;
    if (v < N_VERT) {
      const int4 pb0 = *(const int4*)(point_buf + (size_t)v*8);
      const int4 pb1 = *(const int4*)(point_buf + (size_t)v*8 + 4);
      const float* fn = fnS + bg*FNS + bsub*4;
      float4 g0 = *(const float4*)(fn + (size_t)pb0.x*16);
      float4 g1 = *(const float4*)(fn + (size_t)pb0.y*16);
      float4 g2 = *(const float4*)(fn + (size_t)pb0.z*16);
      float4 g3 = *(const float4*)(fn + (size_t)pb0.w*16);
      float4 g4 = *(const float4*)(fn + (size_t)pb1.x*16);
      float4 g5 = *(const float4*)(fn + (size_t)pb1.y*16);
      float4 g6 = *(const float4*)(fn + (size_t)pb1.z*16);
      float4 g7 = *(const float4*)(fn + (size_t)pb1.w*16);
      float sx = ((g0.x+g1.x)+(g2.x+g3.x)) + ((g4.x+g5.x)+(g6.x+g7.x));
      float sy = ((g0.y+g1.y)+(g2.y+g3.y)) + ((g4.y+g5.y)+(g6.y+g7.y));
      float sz = ((g0.z+g1.z)+(g2.z+g3.z)) + ((g4.z+g5.z)+(g6.z+g7.z));
      float inv = 1.0f / fmaxf(sqrtf(sx*sx + sy*sy + sz*sz), 1e-12f);
      float n0 = sx*inv, n1 = sy*inv, n2 = sz*inv;
      const float* rot = rotAll + b*9;
      float r00=rot[0], r01=rot[1], r02=rot[2];
      float r10=rot[3], r11=rot[4], r12=rot[5];
      float r20=rot[6], r21=rot[7], r22=rot[8];
      float nx = n0*r00 + n1*r10 + n2*r20;
      float ny = n0*r01 + n1*r11 + n2*r21;
      float nz = n0*r02 + n1*r12 + n2*r22;
      float Y1 = -A1C1*ny;
      float Y2 =  A1C1*nz;
      float Y3 = -A1C1*nx;
      float Y4 =  A2C2*nx*ny;
      float Y5 = -A2C2*ny*nz;
      float Y6 =  Y6C*(3.f*nz*nz - 1.f);
      float Y7 = -A2C2*nx*nz;
      float Y8 =  Y8C*(nx*nx - ny*ny);
      const float* g = gAll + b*27;
      #pragma unroll
      for (int c = 0; c < 3; ++c) {
        const float* gc = g + c*9;
        LL[bsub*193 + vi*3 + c] =
            A0C0*gc[0] + Y1*gc[1] + Y2*gc[2] + Y3*gc[3] + Y4*gc[4]
          + Y5*gc[5] + Y6*gc[6] + Y7*gc[7] + Y8*gc[8];
      }
      float4 fsv = *(const float4*)(fsS + bg*FSS + (size_t)v*16 + bsub*4);
      const float* tre = treAll + b*3;
      fstL[bsub*193 + vi*3 + 0] = fsv.x*r00 + fsv.y*r10 + fsv.z*r20 + tre[0];
      fstL[bsub*193 + vi*3 + 1] = fsv.x*r01 + fsv.y*r11 + fsv.z*r21 + tre[1];
      fstL[bsub*193 + vi*3 + 2] = fsv.x*r02 + fsv.y*r12 + fsv.z*r22 + tre[2];
    }
    __syncthreads();
    // writeout: 4 batches x 192 consecutive floats
    int b2 = t >> 6, w = t & 63;
    if (v0 + w < N_VERT) {
      int bb = bg*4 + b2;
      size_t obase = (size_t)bb*M3 + (size_t)(v0 + w)*3;
      #pragma unroll
      for (int c = 0; c < 3; ++c)
        __builtin_nontemporal_store(fstL[b2*193 + w*3 + c], &out[FST_OFF + obase + c]);
      #pragma unroll
      for (int c = 0; c < 3; ++c) {
        float tx = out[FC_OFF + obase + c];
        __builtin_nontemporal_store(tx*LL[b2*193 + w*3 + c], &out[FC_OFF + obase + c]);
      }
    }
  } else {
    int idx = (bid - mainBlocks)*256 + t;
    if (idx >= NB*68) return;
    int b = idx & 31, j = idx >> 5;
    int kp = keypoints[j];
    const float* rot = rotAll + b*9;
    const float* tre = treAll + b*3;
    float4 fsv = *(const float4*)(fsS + (size_t)(b>>2)*FSS + (size_t)kp*16 + (b&3)*4);
    float o0 = fsv.x*rot[0] + fsv.y*rot[3] + fsv.z*rot[6] + tre[0];
    float o1 = fsv.x*rot[1] + fsv.y*rot[4] + fsv.z*rot[7] + tre[1];
    float o2 = fsv.x*rot[2] + fsv.y*rot[5] + fsv.z*rot[8] + tre[2];
    float zc = 10.0f - o2;
    float axv = 1015.0f*o0 + 112.0f*zc;
    float ayv = 1015.0f*o1 + 112.0f*zc;
    __builtin_nontemporal_store(axv/zc, &out[LM_OFF + (size_t)b*136 + (size_t)j*2 + 0]);
    __builtin_nontemporal_store(ayv/zc, &out[LM_OFF + (size_t)b*136 + (size_t)j*2 + 1]);
  }
}

// ======================= launch =======================
extern "C" void kernel_launch(void* const* d_in, const int* in_sizes, int n_in,
                              void* d_out, int out_size, void* d_ws, size_t ws_size,
                              hipStream_t stream) {
  const float* coeff     = (const float*)d_in[0];
  const float* idB       = (const float*)d_in[1];
  const float* exB       = (const float*)d_in[2];
  const float* texB      = (const float*)d_in[3];
  const float* meanshape = (const float*)d_in[4];
  const float* meantex   = (const float*)d_in[5];
  const int*   face_buf  = (const int*)d_in[6];
  const int*   point_buf = (const int*)d_in[7];
  const int*   keypoints = (const int*)d_in[8];
  float* out = (float*)d_out;
  float* ws  = (float*)d_ws;

  (void)hipMemsetAsync((char*)d_ws + WS_MEAN*sizeof(float), 0, 3*sizeof(float), stream);

  hipLaunchKernelGGL(face3d_stageA1, dim3(56), dim3(256), 0, stream, meanshape, ws);
  hipLaunchKernelGGL(face3d_stageA2, dim3(1), dim3(256), 0, stream, coeff, ws);

  int gridB = (M3 + 511)/512;            // 210
  hipLaunchKernelGGL(face3d_stageB, dim3(gridB), dim3(256), 0, stream,
                     idB, exB, texB, meanshape, meantex,
                     ws + WS_CPAD, ws + WS_FS, out + FC_OFF);

  int gridC = 8 * ((N_FACE + 1 + 63)/64);   // 8 * 1107
  hipLaunchKernelGGL(face3d_stageC, dim3(gridC), dim3(256), 0, stream,
                     face_buf, ws + WS_FS, ws + WS_FN);

  int mainBlocks = 8*DVB;                 // 4464
  int lmBlocks   = (NB*68 + 255)/256;     // 9
  hipLaunchKernelGGL(face3d_stageD, dim3(mainBlocks + lmBlocks), dim3(256), 0, stream,
                     point_buf, keypoints, ws + WS_FS, ws + WS_FN,
                     ws + WS_ROT, ws + WS_TRE, ws + WS_G, out);
}